// Round 9
// baseline (229.882 us; speedup 1.0000x reference)
//
#include <hip/hip_runtime.h>
#include <stdint.h>

// YOLO v1 loss, fp32. preds/labels: [B, 7, 7, 30] fp32. Output: scalar fp32.
// Staging via __builtin_amdgcn_global_load_lds with 16-BYTE ops ONLY
// (width-12 LDS lane-stride is unverified HW behavior and was the r8 bug):
// each wave stages 32 cells x both arrays into a wave-private 8 KiB LDS
// region with 8 dma16 ops (the 4th per array over-reads 256 B into the
// next cells -- in-bounds while rem >= 35, else cold tail path).
// One vmcnt(0) per chunk; lanes 0-31 extract+compute. LDS = 32768 B/block
// exactly -> 5 blocks/CU (160 KiB), 20 waves/CU hide DMA latency.
// Reduction scratch reuses buf after a block barrier. Fused deterministic
// last-block finalize.

#define LAMBDA_COORD 5.0f
#define LAMBDA_NOOBJ 0.5f

typedef const __attribute__((address_space(1))) uint32_t* gas_ptr;
typedef __attribute__((address_space(3))) uint32_t* las_ptr;

__device__ __forceinline__ void dma16(const void* g, void* l) {
    __builtin_amdgcn_global_load_lds((gas_ptr)g, (las_ptr)l, 16, 0, 0);
}

__device__ __forceinline__ float iou_xywh(const float* b1, const float* b2) {
    float b1x1 = b1[0] - b1[2] * 0.5f;
    float b1y1 = b1[1] - b1[3] * 0.5f;
    float b1x2 = b1[0] + b1[2] * 0.5f;
    float b1y2 = b1[1] + b1[3] * 0.5f;
    float b2x1 = b2[0] - b2[2] * 0.5f;
    float b2y1 = b2[1] - b2[3] * 0.5f;
    float b2x2 = b2[0] + b2[2] * 0.5f;
    float b2y2 = b2[1] + b2[3] * 0.5f;
    float iw = fmaxf(fminf(b1x2, b2x2) - fmaxf(b1x1, b2x1), 0.0f);
    float ih = fmaxf(fminf(b1y2, b2y2) - fmaxf(b1y1, b2y1), 0.0f);
    float inter = iw * ih;
    float area1 = (b1x2 - b1x1) * (b1y2 - b1y1);
    float area2 = (b2x2 - b2x1) * (b2y2 - b2y1);
    return inter / (area1 + area2 - inter + 1e-10f);
}

__device__ __forceinline__ float cell_loss(const float* __restrict__ p,
                                           const float* __restrict__ l) {
    bool obj  = (l[4] == 1.0f);
    float iou1 = iou_xywh(p + 0, l + 0);
    float iou2 = iou_xywh(p + 5, l + 0);
    bool box1 = (iou1 > iou2);

    float dx1 = l[0] - p[0], dy1 = l[1] - p[1];
    float xy1 = dx1 * dx1 + dy1 * dy1;
    float dx2 = l[5] - p[5], dy2 = l[6] - p[6];
    float xy2 = dx2 * dx2 + dy2 * dy2;

    float dw1 = sqrtf(l[2]) - sqrtf(p[2]);
    float dh1 = sqrtf(l[3]) - sqrtf(p[3]);
    float wh1 = dw1 * dw1 + dh1 * dh1;
    float dw2 = sqrtf(l[7]) - sqrtf(p[7]);
    float dh2 = sqrtf(l[8]) - sqrtf(p[8]);
    float wh2 = dw2 * dw2 + dh2 * dh2;

    float dc1 = l[4] - p[4];
    float conf1 = dc1 * dc1;
    float dc2 = l[9] - p[9];
    float conf2 = dc2 * dc2;

    float cls = 0.0f;
    #pragma unroll
    for (int k = 10; k < 30; ++k) {
        float d = l[k] - p[k];
        cls = fmaf(d, d, cls);
    }

    if (obj) {
        float xy  = box1 ? xy1 : xy2;
        float wh  = box1 ? wh1 : wh2;
        float cf  = box1 ? conf1 : conf2;
        float no  = box1 ? p[9] * p[9] : p[4] * p[4];
        return LAMBDA_COORD * (xy + wh) + cf + LAMBDA_NOOBJ * no + cls;
    } else {
        return LAMBDA_NOOBJ * (p[4] * p[4] + p[9] * p[9]);
    }
}

__device__ __forceinline__ float block_reduce_sum(float v, float* smem) {
    #pragma unroll
    for (int off = 32; off > 0; off >>= 1)
        v += __shfl_down(v, off, 64);
    int lane = threadIdx.x & 63;
    int wid  = threadIdx.x >> 6;
    if (lane == 0) smem[wid] = v;
    __syncthreads();
    float total = 0.0f;
    if (threadIdx.x == 0) {
        int nw = blockDim.x >> 6;
        for (int i = 0; i < nw; ++i) total += smem[i];
    }
    return total;  // valid only on thread 0
}

__global__ void __launch_bounds__(256) yolo_loss(
        const float* __restrict__ preds,
        const float* __restrict__ labels,
        float* __restrict__ out,
        float* __restrict__ partial,
        unsigned int* __restrict__ counter,
        int ncells, float inv_batch) {
    // per-wave private 8 KiB: [0,4096) preds (32 cells + 256B overrun),
    //                         [4096,8192) labels
    __shared__ alignas(16) char buf[4][8192];   // 32768 B exactly
    int tid  = threadIdx.x;
    int lane = tid & 63;
    int wid  = tid >> 6;
    char* sb = buf[wid];

    int nbc = (ncells + 127) >> 7;              // block-chunks of 128 cells
    float acc = 0.0f;

    for (int bc = blockIdx.x; bc < nbc; bc += gridDim.x) {
        int cell0 = bc * 128 + wid * 32;        // this wave's 32 cells
        int rem = ncells - cell0;
        if (rem <= 0) continue;                 // no barriers in loop -> safe

        if (rem >= 35) {                        // dma16 overrun stays in-bounds
            const char* gp = (const char*)preds  + (size_t)cell0 * 120u;  // 16B-aligned
            const char* gl = (const char*)labels + (size_t)cell0 * 120u;

            // WAR: previous chunk's ds_reads drained before DMA overwrites
            asm volatile("s_waitcnt lgkmcnt(0)" ::: "memory");

            // 8 async 16B DMA ops, zero data VGPRs, all in flight at once
            dma16(gp + lane * 16,        sb);
            dma16(gp + 1024 + lane * 16, sb + 1024);
            dma16(gp + 2048 + lane * 16, sb + 2048);
            dma16(gp + 3072 + lane * 16, sb + 3072);   // 256B overrun
            dma16(gl + lane * 16,        sb + 4096);
            dma16(gl + 1024 + lane * 16, sb + 5120);
            dma16(gl + 2048 + lane * 16, sb + 6144);
            dma16(gl + 3072 + lane * 16, sb + 7168);   // 256B overrun

            asm volatile("s_waitcnt vmcnt(0)" ::: "memory");

            if (lane < 32) {
                const float2* bp = (const float2*)(sb)        + lane * 15;
                const float2* bl = (const float2*)(sb + 4096) + lane * 15;
                float p[30], l[30];
                #pragma unroll
                for (int i = 0; i < 15; ++i) {
                    float2 t = bp[i];
                    p[2 * i] = t.x; p[2 * i + 1] = t.y;
                }
                #pragma unroll
                for (int i = 0; i < 15; ++i) {
                    float2 t = bl[i];
                    l[2 * i] = t.x; l[2 * i + 1] = t.y;
                }
                acc += cell_loss(p, l);
            }
        } else {
            // cold ragged tail: direct strided loads (r1 pattern)
            if (lane < rem) {
                const float2* gp2 = (const float2*)((const char*)preds  + (size_t)(cell0 + lane) * 120u);
                const float2* gl2 = (const float2*)((const char*)labels + (size_t)(cell0 + lane) * 120u);
                float p[30], l[30];
                #pragma unroll
                for (int i = 0; i < 15; ++i) {
                    float2 tp = gp2[i], tl = gl2[i];
                    p[2 * i] = tp.x; p[2 * i + 1] = tp.y;
                    l[2 * i] = tl.x; l[2 * i + 1] = tl.y;
                }
                acc += cell_loss(p, l);
            }
        }
    }

    // All waves done with buf (incl. their DMAs) -> safe to reuse as scratch
    __syncthreads();
    float* red1  = (float*)buf;          // 4 floats
    float* red2  = (float*)buf + 8;      // 4 floats
    int*   lastf = (int*)((float*)buf + 16);

    float bsum = block_reduce_sum(acc, red1);
    if (tid == 0) {
        partial[blockIdx.x] = bsum;
        __threadfence();
        unsigned int prev = atomicAdd(counter, 1u);
        *lastf = (prev == gridDim.x - 1) ? 1 : 0;
    }
    __syncthreads();

    if (*lastf) {
        __threadfence();
        float a = 0.0f;
        for (int i = tid; i < (int)gridDim.x; i += blockDim.x)
            a += partial[i];                    // fixed order -> deterministic
        float total = block_reduce_sum(a, red2);
        if (tid == 0) out[0] = total * inv_batch;
    }
}

extern "C" void kernel_launch(void* const* d_in, const int* in_sizes, int n_in,
                              void* d_out, int out_size, void* d_ws, size_t ws_size,
                              hipStream_t stream) {
    const float* preds  = (const float*)d_in[0];
    const float* labels = (const float*)d_in[1];
    float* out = (float*)d_out;

    int ncells = in_sizes[0] / 30;              // B * 7 * 7
    int batch  = ncells / 49;
    float inv_batch = 1.0f / (float)batch;

    int nbc = (ncells + 127) >> 7;              // 6272 at B=16384
    int grid = nbc;
    int maxblocks = (int)((ws_size - sizeof(unsigned int)) / sizeof(float));
    if (grid > maxblocks) grid = maxblocks;     // grid-stride covers the rest
    if (grid > 8192) grid = 8192;
    if (grid < 1) grid = 1;

    float* partial = (float*)d_ws;
    unsigned int* counter = (unsigned int*)((char*)d_ws + (size_t)grid * sizeof(float));

    hipMemsetAsync(counter, 0, sizeof(unsigned int), stream);
    yolo_loss<<<grid, 256, 0, stream>>>(preds, labels, out, partial, counter,
                                        ncells, inv_batch);
}